// Round 7
// baseline (183.849 us; speedup 1.0000x reference)
//
#include <hip/hip_runtime.h>

// FilteredNoiseGenerator: B=32, t=4000, nbands=65, framesize=80, L_fir=129, L=208
// out[b,p] = sum_{f,m} x[b,f,m]*w[b,f,tau], tau = (p+64) - 80f - m in [0,128]
// P1 (firwin) = GEMM vs fixed matrix M (MFMA f16, M in d_ws, frag-order).
// R7: w and x stored in LDS as f16 -> 21.1 KB/wg -> 7 wg/CU (28 waves) vs 4.
//     w row stride 158 f16 = 79 dwords, gcd(79,32)=1 -> conflict-free P2 w-reads.

#define NT 256
#define X_STRIDE 84        // f16 x row stride; slot byte stride 168 (8B-aligned rows)
#define W_STRIDE 158       // f16 w row; max read idx 155 (proven); 79 dw, gcd 1
#define W_P 14             // w[tau] at wr[W_P+tau]; tau in [0,128]; zeros outside
#define NSLOT 35           // frames f0-2 .. f0+32
#define WTOT_H 5536        // 35*158 = 5530 f16, padded to mult of 8 for float4 zeroing
#define HF_STRIDE 104      // f16 H row stride (208 B, 16B-aligned b128 frag loads)
#define UTOT_F 2496        // union floats: 48*104 f16 = 9984 B (H) >= 35*84*2 B (x)

typedef _Float16 f16x8 __attribute__((ext_vector_type(8)));
typedef _Float16 f16x4 __attribute__((ext_vector_type(4)));
typedef _Float16 f16x2 __attribute__((ext_vector_type(2)));
typedef float f32x4 __attribute__((ext_vector_type(4)));

// ---- init: M in MFMA B-operand frag order (R6-proven). frag (nt,ks) of 27;
// lane holds B[k = ks*32 + (lane>>4)*8 + j][n = nt*16 + (lane&15)], j=0..7.
__global__ void __launch_bounds__(256)
minit_kernel(_Float16* __restrict__ M) {
  const float TP = 6.28318530717958647692f / 129.f;
  int i = blockIdx.x * 256 + threadIdx.x;      // 54*256 = 13824 = 27*512 exactly
  int frag = i >> 9;
  int off  = i & 511;
  int lane = off >> 3, j = off & 7;
  int nt = frag / 3, ks = frag - 3 * (frag / 3);
  int n = nt * 16 + (lane & 15);
  int k = ks * 32 + (lane >> 4) * 8 + j;
  float v = 0.f;
  if (n <= 128 && k <= 64) {
    float hann = 0.5f - 0.5f * __cosf((float)n * TP);
    float sc = (k == 0 ? 1.f : 2.f) * (1.f / 129.f);
    int e = (k * (n - 64)) % 129; if (e < 0) e += 129;   // exact arg reduction
    v = hann * sc * __cosf((float)e * TP);
  }
  M[i] = (_Float16)v;
}

__global__ void __launch_bounds__(NT)
fng_kernel(const float* __restrict__ Hg_, const float* __restrict__ Ng_,
           float* __restrict__ Og_, const _Float16* __restrict__ Mg) {
  __shared__ __align__(16) _Float16 sWh[WTOT_H];   // 11,072 B (firwin f16, zero-padded)
  __shared__ __align__(16) float sU[UTOT_F];       //  9,984 B: H-f16 (P1), x-f16 (P2)
  // total ~21.1 KB -> 7 wg/CU = 28 waves

  const int t  = threadIdx.x;
  const int bx = blockIdx.x;     // 0..124 (32 output-frames each)
  const int b  = blockIdx.y;     // 0..31
  const int f0 = bx * 32;

  // ---------------- P0: zero sW, H -> f16 LDS, noise -> regs ----------------
  float4 xq[3];                  // parked noise quads (raw; 0.5 -> maps to 0)
  {
    float4 z4 = {0.f, 0.f, 0.f, 0.f};
    for (int i = t; i < WTOT_H / 8; i += NT) ((float4*)sWh)[i] = z4;
    _Float16* sHf = (_Float16*)sU;
    const float* Hg = Hg_ + (size_t)b * (4000 * 65);
    for (int i = t; i < 48 * 96; i += NT) {          // rows 0..47 (pad rows zero)
      int row = i / 96, k = i - 96 * (i / 96);
      int fr = f0 - 2 + row;
      float v = 0.f;
      if (k < 65 && row < NSLOT && fr >= 0 && fr < 4000) v = Hg[fr * 65 + k];
      sHf[row * HF_STRIDE + k] = (_Float16)v;
    }
    const float* Ng = Ng_ + (size_t)b * 320000;
#pragma unroll
    for (int j = 0; j < 3; ++j) {
      int q = t + 256 * j;
      float4 v = {0.5f, 0.5f, 0.5f, 0.5f};          // 2*0.5-1 = 0 for OOB rows
      if (q < NSLOT * 21) {
        int fi = q / 21, qm = q - fi * 21;
        int fr = f0 - 2 + fi;
        if (qm < 20 && fr >= 0 && fr < 4000)
          v = *(const float4*)&Ng[(size_t)fr * 80 + 4 * qm];
      }
      xq[j] = v;
    }
  }
  __syncthreads();

  // ------- P1: firwin = H x M^T via MFMA 16x16x32 f16 (R6-proven layout) -------
  {
    const _Float16* sHf = (const _Float16*)sU;
    const int wv   = t >> 6;
    const int lane = t & 63;
    const int quad = lane >> 4;
    const int l15  = lane & 15;
#pragma unroll 1
    for (int tile = wv; tile < 27; tile += 4) {
      const int mt = tile / 9, nt = tile - 9 * (tile / 9);
      f32x4 acc = {0.f, 0.f, 0.f, 0.f};
#pragma unroll
      for (int ks = 0; ks < 3; ++ks) {
        f16x8 a = *(const f16x8*)&sHf[(mt * 16 + l15) * HF_STRIDE + ks * 32 + quad * 8];
        f16x8 bb = ((const f16x8*)Mg)[(nt * 3 + ks) * 64 + lane];
        acc = __builtin_amdgcn_mfma_f32_16x16x32_f16(a, bb, acc, 0, 0, 0);
      }
      const int n = nt * 16 + l15;
      const int fr0 = mt * 16 + quad * 4;
      if (n <= 128) {
#pragma unroll
        for (int r = 0; r < 4; ++r) {
          int frame = fr0 + r;
          if (frame < NSLOT) sWh[frame * W_STRIDE + W_P + n] = (_Float16)acc[r];
        }
      }
    }
  }
  __syncthreads();

  // ---------------- P1.5: park noise into sU as f16 (overwrites H) ----------------
  {
    _Float16* sXh = (_Float16*)sU;
#pragma unroll
    for (int j = 0; j < 3; ++j) {
      int q = t + 256 * j;
      if (q < NSLOT * 21) {
        int fi = q / 21, qm = q - fi * 21;
        if (qm < 20) {                              // pad quad qm=20 never read
          float4 v = xq[j];
          f16x4 o;
          o.x = (_Float16)(2.f * v.x - 1.f); o.y = (_Float16)(2.f * v.y - 1.f);
          o.z = (_Float16)(2.f * v.z - 1.f); o.w = (_Float16)(2.f * v.w - 1.f);
          *(f16x4*)&sXh[fi * X_STRIDE + 4 * qm] = o;
        }
      }
    }
  }
  __syncthreads();

  // ---------------- P2: gather convolution (f16 LDS) + direct stores ----------------
  {
    const _Float16* sXh = (const _Float16*)sU;
    const int col = t & 31;
    const int pb  = t >> 5;
    const int e   = 64 + 10 * pb;
    const int qq  = (e >= 80) ? 1 : 0;
    const int D   = e - 80 * qq;                    // per half-wave uniform, even
    float acc[10];
#pragma unroll
    for (int i = 0; i < 10; ++i) acc[i] = 0.f;

#pragma unroll 1
    for (int g = 2; g >= -1; --g) {                 // source frame F - g
      const int dlt = D + 80 * g;                   // even
      int Qlo = (dlt - 131 + 3) >> 2; if (Qlo < 0) Qlo = 0;
      int Qhi = (dlt + 9) >> 2;       if (Qhi > 19) Qhi = 19;
      if (Qlo > Qhi) continue;
      const int slot = col + qq - g + 2;            // 0..34
      const _Float16* wr = &sWh[slot * W_STRIDE];
      const _Float16* xr = &sXh[slot * X_STRIDE];
      int wb = W_P + dlt - 4 * Qlo - 4;             // even, >= 0; max idx 155 proven
      float wv[16];
#pragma unroll
      for (int k = 0; k < 8; ++k) {
        f16x2 w2 = *(const f16x2*)&wr[wb + 2 * k];  // 4B-aligned
        wv[2 * k] = (float)w2.x; wv[2 * k + 1] = (float)w2.y;
      }
#pragma unroll 4                                    // period-4 rotation renames movs away
      for (int Q = Qlo; Q <= Qhi; ++Q) {
        f16x4 x4 = *(const f16x4*)&xr[4 * Q];       // 8B-aligned
        const float xv[4] = {(float)x4.x, (float)x4.y, (float)x4.z, (float)x4.w};
#pragma unroll
        for (int mm = 0; mm < 4; ++mm)
#pragma unroll
          for (int i = 0; i < 10; ++i)
            acc[i] = fmaf(xv[mm], wv[i - mm + 4], acc[i]);   // static idx in [1,13]
        wb -= 4; int wc = (wb < 0) ? 0 : wb;        // slide (clamped; pads are zeros)
#pragma unroll
        for (int k = 15; k >= 4; --k) wv[k] = wv[k - 4];
        f16x2 wA = *(const f16x2*)&wr[wc];
        f16x2 wB = *(const f16x2*)&wr[wc + 2];
        wv[0] = (float)wA.x; wv[1] = (float)wA.y;
        wv[2] = (float)wB.x; wv[3] = (float)wB.y;
      }
    }

    // exactly-once writeout: u0 = 80*col + 10*pb (even -> float2 stores)
    float* Ob = Og_ + (size_t)b * 320000 + 2560 * bx + 80 * col + 10 * pb;
#pragma unroll
    for (int s = 0; s < 5; ++s) {
      float2 v; v.x = acc[2 * s]; v.y = acc[2 * s + 1];
      *(float2*)&Ob[2 * s] = v;
    }
  }
}

extern "C" void kernel_launch(void* const* d_in, const int* in_sizes, int n_in,
                              void* d_out, int out_size, void* d_ws, size_t ws_size,
                              hipStream_t stream) {
  const float* H     = (const float*)d_in[0];   // [32,4000,65] fp32
  const float* noise = (const float*)d_in[1];   // [32,4000,80] fp32
  float* out = (float*)d_out;                   // [32,320000] fp32
  _Float16* M = (_Float16*)d_ws;                // 27,648 B of scratch
  (void)in_sizes; (void)n_in; (void)ws_size; (void)out_size;

  minit_kernel<<<54, 256, 0, stream>>>(M);      // rebuilt every call (ws re-poisoned)
  dim3 grid(125, 32, 1);
  fng_kernel<<<grid, NT, 0, stream>>>(H, noise, out, M);
}

// Round 8
// 170.048 us; speedup vs baseline: 1.0812x; 1.0812x over previous
//
#include <hip/hip_runtime.h>

// FilteredNoiseGenerator: B=32, t=4000, nbands=65, framesize=80, L_fir=129, L=208
// out[b,p] = sum_{f,m} x[b,f,m]*w[b,f,tau], tau = (p+64) - 80f - m in [0,128]
// P1 (firwin) = GEMM vs fixed matrix M (MFMA f16, M in d_ws, frag-order).
// R8: P2 inner loop via v_dot2_f32_f16 (__builtin_amdgcn_fdot2): 2 f16 MACs/inst,
//     f32 accumulate. w-window kept as f16x2 pairs (even-aligned wE loaded b32,
//     odd-aligned wO via v_alignbit). ~1.9x fewer P2 VALU inst than R7.

#define NT 256
#define X_STRIDE 84        // f16 x row stride; slot byte stride 168 (8B-aligned rows)
#define W_STRIDE 158       // f16 w row; 79 dw/row, gcd(79,32)=1 -> conflict-free
#define W_P 14             // w[tau] at wr[W_P+tau]; tau in [0,128]; zeros outside
#define NSLOT 35           // frames f0-2 .. f0+32
#define WTOT_H 5536        // 35*158 = 5530 f16, padded to mult of 8
#define HF_STRIDE 104      // f16 H row stride (208 B, 16B-aligned b128 frag loads)
#define UTOT_F 2496        // union floats: 48*104 f16 (H) >= 35*84 f16 (x)

typedef _Float16 f16x8 __attribute__((ext_vector_type(8)));
typedef _Float16 f16x4 __attribute__((ext_vector_type(4)));
typedef _Float16 h2 __attribute__((ext_vector_type(2)));
typedef float f32x4 __attribute__((ext_vector_type(4)));

union U32H2 { unsigned u; h2 h; };
static __device__ __forceinline__ h2 swap_h2(h2 v) {           // (v.y, v.x)
  U32H2 a; a.h = v;
  U32H2 o; o.u = __builtin_amdgcn_alignbit(a.u, a.u, 16);
  return o.h;
}
static __device__ __forceinline__ h2 mid_h2(h2 lo, h2 hi) {    // (lo.y, hi.x)
  U32H2 a, b; a.h = lo; b.h = hi;
  U32H2 o; o.u = __builtin_amdgcn_alignbit(b.u, a.u, 16);
  return o.h;
}

// ---- init: M in MFMA B-operand frag order (R6-proven). frag (nt,ks) of 27;
// lane holds B[k = ks*32 + (lane>>4)*8 + j][n = nt*16 + (lane&15)], j=0..7.
__global__ void __launch_bounds__(256)
minit_kernel(_Float16* __restrict__ M) {
  const float TP = 6.28318530717958647692f / 129.f;
  int i = blockIdx.x * 256 + threadIdx.x;      // 54*256 = 13824 = 27*512 exactly
  int frag = i >> 9;
  int off  = i & 511;
  int lane = off >> 3, j = off & 7;
  int nt = frag / 3, ks = frag - 3 * (frag / 3);
  int n = nt * 16 + (lane & 15);
  int k = ks * 32 + (lane >> 4) * 8 + j;
  float v = 0.f;
  if (n <= 128 && k <= 64) {
    float hann = 0.5f - 0.5f * __cosf((float)n * TP);
    float sc = (k == 0 ? 1.f : 2.f) * (1.f / 129.f);
    int e = (k * (n - 64)) % 129; if (e < 0) e += 129;   // exact arg reduction
    v = hann * sc * __cosf((float)e * TP);
  }
  M[i] = (_Float16)v;
}

__global__ void __launch_bounds__(NT)
fng_kernel(const float* __restrict__ Hg_, const float* __restrict__ Ng_,
           float* __restrict__ Og_, const _Float16* __restrict__ Mg) {
  __shared__ __align__(16) _Float16 sWh[WTOT_H];   // 11,072 B (firwin f16, zero-padded)
  __shared__ __align__(16) float sU[UTOT_F];       //  9,984 B: H-f16 (P1), x-f16 (P2)

  const int t  = threadIdx.x;
  const int bx = blockIdx.x;     // 0..124 (32 output-frames each)
  const int b  = blockIdx.y;     // 0..31
  const int f0 = bx * 32;

  // ---------------- P0: zero sW, H -> f16 LDS, noise -> regs ----------------
  float4 xq[3];                  // parked noise quads (raw; 0.5 -> maps to 0)
  {
    float4 z4 = {0.f, 0.f, 0.f, 0.f};
    for (int i = t; i < WTOT_H / 8; i += NT) ((float4*)sWh)[i] = z4;
    _Float16* sHf = (_Float16*)sU;
    const float* Hg = Hg_ + (size_t)b * (4000 * 65);
    for (int i = t; i < 48 * 96; i += NT) {          // rows 0..47 (pad rows zero)
      int row = i / 96, k = i - 96 * (i / 96);
      int fr = f0 - 2 + row;
      float v = 0.f;
      if (k < 65 && row < NSLOT && fr >= 0 && fr < 4000) v = Hg[fr * 65 + k];
      sHf[row * HF_STRIDE + k] = (_Float16)v;
    }
    const float* Ng = Ng_ + (size_t)b * 320000;
#pragma unroll
    for (int j = 0; j < 3; ++j) {
      int q = t + 256 * j;
      float4 v = {0.5f, 0.5f, 0.5f, 0.5f};          // 2*0.5-1 = 0 for OOB rows
      if (q < NSLOT * 21) {
        int fi = q / 21, qm = q - fi * 21;
        int fr = f0 - 2 + fi;
        if (qm < 20 && fr >= 0 && fr < 4000)
          v = *(const float4*)&Ng[(size_t)fr * 80 + 4 * qm];
      }
      xq[j] = v;
    }
  }
  __syncthreads();

  // ------- P1: firwin = H x M^T via MFMA 16x16x32 f16 (R6-proven layout) -------
  {
    const _Float16* sHf = (const _Float16*)sU;
    const int wv   = t >> 6;
    const int lane = t & 63;
    const int quad = lane >> 4;
    const int l15  = lane & 15;
#pragma unroll 1
    for (int tile = wv; tile < 27; tile += 4) {
      const int mt = tile / 9, nt = tile - 9 * (tile / 9);
      f32x4 acc = {0.f, 0.f, 0.f, 0.f};
#pragma unroll
      for (int ks = 0; ks < 3; ++ks) {
        f16x8 a = *(const f16x8*)&sHf[(mt * 16 + l15) * HF_STRIDE + ks * 32 + quad * 8];
        f16x8 bb = ((const f16x8*)Mg)[(nt * 3 + ks) * 64 + lane];
        acc = __builtin_amdgcn_mfma_f32_16x16x32_f16(a, bb, acc, 0, 0, 0);
      }
      const int n = nt * 16 + l15;
      const int fr0 = mt * 16 + quad * 4;
      if (n <= 128) {
#pragma unroll
        for (int r = 0; r < 4; ++r) {
          int frame = fr0 + r;
          if (frame < NSLOT) sWh[frame * W_STRIDE + W_P + n] = (_Float16)acc[r];
        }
      }
    }
  }
  __syncthreads();

  // ---------------- P1.5: park noise into sU as f16 (overwrites H) ----------------
  {
    _Float16* sXh = (_Float16*)sU;
#pragma unroll
    for (int j = 0; j < 3; ++j) {
      int q = t + 256 * j;
      if (q < NSLOT * 21) {
        int fi = q / 21, qm = q - fi * 21;
        if (qm < 20) {                              // pad quad qm=20 never read
          float4 v = xq[j];
          f16x4 o;
          o.x = (_Float16)(2.f * v.x - 1.f); o.y = (_Float16)(2.f * v.y - 1.f);
          o.z = (_Float16)(2.f * v.z - 1.f); o.w = (_Float16)(2.f * v.w - 1.f);
          *(f16x4*)&sXh[fi * X_STRIDE + 4 * qm] = o;
        }
      }
    }
  }
  __syncthreads();

  // ------- P2: gather convolution via v_dot2_f32_f16 + direct stores -------
  {
    const _Float16* sXh = (const _Float16*)sU;
    const int col = t & 31;
    const int pb  = t >> 5;
    const int e   = 64 + 10 * pb;
    const int qq  = (e >= 80) ? 1 : 0;
    const int D   = e - 80 * qq;                    // per half-wave uniform, even
    float acc[10];
#pragma unroll
    for (int i = 0; i < 10; ++i) acc[i] = 0.f;

#pragma unroll 1
    for (int g = 2; g >= -1; --g) {                 // source frame F - g
      const int dlt = D + 80 * g;                   // even
      int Qlo = (dlt - 131 + 3) >> 2; if (Qlo < 0) Qlo = 0;
      int Qhi = (dlt + 9) >> 2;       if (Qhi > 19) Qhi = 19;
      if (Qlo > Qhi) continue;
      const int slot = col + qq - g + 2;            // 0..34
      const _Float16* wr = &sWh[slot * W_STRIDE];
      const _Float16* xr = &sXh[slot * X_STRIDE];
      int wb = W_P + dlt - 4 * Qlo - 4;             // even, >= 0; max wb+13 <= 155

      // w-window as f16x2 pairs: wE[k] = (w[wb+2k], w[wb+2k+1]) even-aligned,
      // wO[k] = (w[wb+2k+1], w[wb+2k+2]) odd-aligned. Used pair range k in [1,12].
      h2 wE[7], wO[6];
#pragma unroll
      for (int k = 0; k < 7; ++k) wE[k] = *(const h2*)&wr[wb + 2 * k];  // 4B-aligned
#pragma unroll
      for (int k = 0; k < 6; ++k) wO[k] = mid_h2(wE[k], wE[k + 1]);

#define PAIR(K) (((K) & 1) ? wO[((K) - 1) >> 1] : wE[(K) >> 1])
#pragma unroll 4
      for (int Q = Qlo; Q <= Qhi; ++Q) {
        f16x4 x4 = *(const f16x4*)&xr[4 * Q];       // 8B-aligned b64
        h2 x01; x01.x = x4.x; x01.y = x4.y;
        h2 x23; x23.x = x4.z; x23.y = x4.w;
        h2 xs01 = swap_h2(x01);                     // (x1, x0)
        h2 xs23 = swap_h2(x23);                     // (x3, x2)
#pragma unroll
        for (int i = 0; i < 10; ++i) {
          // m-pair (0,1): x0*w[wb+i+4] + x1*w[wb+i+3] = dot2(xs01, p(i+3))
          acc[i] = __builtin_amdgcn_fdot2(xs01, PAIR(i + 3), acc[i], false);
          // m-pair (2,3): x2*w[wb+i+2] + x3*w[wb+i+1] = dot2(xs23, p(i+1))
          acc[i] = __builtin_amdgcn_fdot2(xs23, PAIR(i + 1), acc[i], false);
        }
        // slide window down 4 w-values = 2 pair-slots (clamped; pads are zeros)
        wb -= 4; int wc = (wb < 0) ? 0 : wb;
#pragma unroll
        for (int k = 6; k >= 2; --k) wE[k] = wE[k - 2];
#pragma unroll
        for (int k = 5; k >= 2; --k) wO[k] = wO[k - 2];
        wE[0] = *(const h2*)&wr[wc];
        wE[1] = *(const h2*)&wr[wc + 2];
        wO[0] = mid_h2(wE[0], wE[1]);
        wO[1] = mid_h2(wE[1], wE[2]);
      }
#undef PAIR
    }

    // exactly-once writeout: u0 = 80*col + 10*pb (even -> float2 stores)
    float* Ob = Og_ + (size_t)b * 320000 + 2560 * bx + 80 * col + 10 * pb;
#pragma unroll
    for (int s = 0; s < 5; ++s) {
      float2 v; v.x = acc[2 * s]; v.y = acc[2 * s + 1];
      *(float2*)&Ob[2 * s] = v;
    }
  }
}

extern "C" void kernel_launch(void* const* d_in, const int* in_sizes, int n_in,
                              void* d_out, int out_size, void* d_ws, size_t ws_size,
                              hipStream_t stream) {
  const float* H     = (const float*)d_in[0];   // [32,4000,65] fp32
  const float* noise = (const float*)d_in[1];   // [32,4000,80] fp32
  float* out = (float*)d_out;                   // [32,320000] fp32
  _Float16* M = (_Float16*)d_ws;                // 27,648 B of scratch
  (void)in_sizes; (void)n_in; (void)ws_size; (void)out_size;

  minit_kernel<<<54, 256, 0, stream>>>(M);      // rebuilt every call (ws re-poisoned)
  dim3 grid(125, 32, 1);
  fng_kernel<<<grid, NT, 0, stream>>>(H, noise, out, M);
}